// Round 3
// baseline (641.408 us; speedup 1.0000x reference)
//
#include <hip/hip_runtime.h>

// SimpleNet: per-pixel MLP, B=4,C=3,H=W=1024 fp32.
// R3: weights pre-duplicated to (w,w) 64-bit pairs in d_ws by a prep kernel so
//     v_pk_fma_f32 can take the uniform weight as an even-aligned SGPR-pair
//     operand directly (R2 burned ~11k cyc/wave building broadcasts with v_mov).
//     Activation input scales (2*log2e for tanh, -log2e for sigmoid) folded
//     into the weights by the prep kernel.

#define HW_PIX (1024 * 1024)
#define NPIX   (4 * HW_PIX)
#define HID    25
#define DEPTH  6

#define N_WIN  (HID * 3)            // 75
#define N_WS   (DEPTH * HID * HID)  // 3750
#define N_WOUT (3 * HID)            // 75
#define N_ALL  (N_WIN + N_WS + N_WOUT)  // 3900 pairs = 31.2 KB

typedef float f2 __attribute__((ext_vector_type(2)));

// --- prep: duplicate + scale weights into d_ws as f2 pairs -------------------
__global__ __launch_bounds__(256) void pack_weights(
    const float* __restrict__ w_in, const float* __restrict__ ws,
    const float* __restrict__ w_out, f2* __restrict__ wp)
{
    int i = blockIdx.x * 256 + threadIdx.x;
    if (i >= N_ALL) return;
    const float TANH_SCALE = 2.8853900817779268f;   // 2*log2(e)
    const float SIG_SCALE  = -1.4426950408889634f;  // -log2(e)
    float w;
    if (i < N_WIN)               w = w_in[i] * TANH_SCALE;
    else if (i < N_WIN + N_WS)   w = ws[i - N_WIN] * TANH_SCALE;
    else                         w = w_out[i - N_WIN - N_WS] * SIG_SCALE;
    f2 p; p.x = w; p.y = w;
    wp[i] = p;
}

// tanh from pre-scaled acc (acc = 2*log2e * y): tanh(y) = 1 - 2*rcp(exp2(acc)+1)
__device__ __forceinline__ f2 tanh_from_scaled(f2 acc) {
    f2 e;
    e.x = __builtin_amdgcn_exp2f(acc.x);
    e.y = __builtin_amdgcn_exp2f(acc.y);
    f2 d = e + 1.0f;
    f2 r;
    r.x = __builtin_amdgcn_rcpf(d.x);
    r.y = __builtin_amdgcn_rcpf(d.y);
    f2 m2 = -2.0f, one = 1.0f;
    return __builtin_elementwise_fma(m2, r, one);
}

// sigmoid from pre-scaled acc (acc = -log2e * y): sigmoid(y) = rcp(exp2(acc)+1)
__device__ __forceinline__ f2 sigmoid_from_scaled(f2 acc) {
    f2 e;
    e.x = __builtin_amdgcn_exp2f(acc.x);
    e.y = __builtin_amdgcn_exp2f(acc.y);
    f2 d = e + 1.0f;
    f2 r;
    r.x = __builtin_amdgcn_rcpf(d.x);
    r.y = __builtin_amdgcn_rcpf(d.y);
    return r;
}

__global__ __launch_bounds__(256, 1) void simplenet_kernel(
    const float* __restrict__ x,    // [4,3,1024,1024]
    const f2* __restrict__ wp,      // packed pairs: [75 w_in | 3750 ws | 75 w_out]
    float* __restrict__ out)        // [4,3,1024,1024]
{
    const int pp  = blockIdx.x * 256 + threadIdx.x;     // pixel-pair id
    const int b   = pp >> 19;
    const int hwp = pp & (HW_PIX / 2 - 1);

    const f2* xb = (const f2*)(x + (size_t)b * 3 * HW_PIX) + hwp;
    const f2 x0 = xb[0 * (HW_PIX / 2)];
    const f2 x1 = xb[1 * (HW_PIX / 2)];
    const f2 x2 = xb[2 * (HW_PIX / 2)];

    f2 h[HID];

    // input layer: 25x3 (weight pairs are uniform -> s_load_dwordx2, SGPR-pair src)
#pragma unroll
    for (int o = 0; o < HID; ++o) {
        f2 acc = wp[o * 3 + 0] * x0;
        acc = __builtin_elementwise_fma(wp[o * 3 + 1], x1, acc);
        acc = __builtin_elementwise_fma(wp[o * 3 + 2], x2, acc);
        h[o] = tanh_from_scaled(acc);
    }

    // 6 hidden layers: 25x25
    for (int l = 0; l < DEPTH; ++l) {
        const f2* __restrict__ wl = wp + N_WIN + l * HID * HID;
        f2 nh[HID];
#pragma unroll
        for (int o = 0; o < HID; ++o) {
            f2 acc = wl[o * HID] * h[0];
#pragma unroll
            for (int c = 1; c < HID; ++c)
                acc = __builtin_elementwise_fma(wl[o * HID + c], h[c], acc);
            nh[o] = acc;
        }
#pragma unroll
        for (int o = 0; o < HID; ++o)
            h[o] = tanh_from_scaled(nh[o]);
    }

    // output layer: 3x25 + sigmoid
    const f2* __restrict__ wo = wp + N_WIN + N_WS;
    f2* ob = (f2*)(out + (size_t)b * 3 * HW_PIX) + hwp;
#pragma unroll
    for (int o = 0; o < 3; ++o) {
        f2 acc = wo[o * HID] * h[0];
#pragma unroll
        for (int c = 1; c < HID; ++c)
            acc = __builtin_elementwise_fma(wo[o * HID + c], h[c], acc);
        ob[o * (HW_PIX / 2)] = sigmoid_from_scaled(acc);
    }
}

extern "C" void kernel_launch(void* const* d_in, const int* in_sizes, int n_in,
                              void* d_out, int out_size, void* d_ws, size_t ws_size,
                              hipStream_t stream) {
    const float* x     = (const float*)d_in[0];
    const float* w_in  = (const float*)d_in[1];
    const float* ws    = (const float*)d_in[2];
    const float* w_out = (const float*)d_in[3];
    float* out         = (float*)d_out;
    f2* wp             = (f2*)d_ws;  // 3900 pairs = 31.2 KB scratch

    hipLaunchKernelGGL(pack_weights, dim3((N_ALL + 255) / 256), dim3(256), 0, stream,
                       w_in, ws, w_out, wp);

    const int threads = 256;
    const int blocks  = (NPIX / 2) / threads;  // 8192, exact
    hipLaunchKernelGGL(simplenet_kernel, dim3(blocks), dim3(threads), 0, stream,
                       x, wp, out);
}

// Round 5
// 313.384 us; speedup vs baseline: 2.0467x; 2.0467x over previous
//
#include <hip/hip_runtime.h>

// SimpleNet R5 (= R4 with __fp16 types): per-pixel MLP via MFMA f16.
//   h = tanh(W_in[25x3] x); 6x: h = tanh(W[25x25] h); out = sigmoid(W_out[3x25] h)
// Layers as D[m=out_ch][n=pixel] = A[m][k] * B[k][n], mfma_f32_16x16x32_f16,
// 2 M-tiles (25 out-ch -> 32 padded), 2 N-tiles (32 px/wave-iter), K=32 (25 padded).
//
// KEY: prep kernel relabels A's k-columns by mu(k) = (k&7)<4 ? 4*(k>>3)+(k&3)
//      : 16+4*(k>>3)+(k&3). Then lane-group g's D regs (rows 4g..4g+3, tiles 0/1)
//      are EXACTLY next layer's B elements (k=8g..8g+7): tile0 regs -> j=0..3,
//      tile1 regs -> j=4..7. No LDS / shuffle between layers.
// Weights pre-scaled: hidden/input *2*log2e (tanh = 1-2*rcp(exp2(acc)+1)),
// output *-log2e (sigmoid = rcp(exp2(acc)+1)).

#define HW_PIX (1024 * 1024)
#define NPIX   (4 * HW_PIX)
#define HID    25
#define DEPTH  6

#define TANH_SCALE 2.8853900817779268f    // 2*log2(e)
#define SIG_SCALE  (-1.4426950408889634f) // -log2(e)

typedef __fp16 h8 __attribute__((ext_vector_type(8)));
typedef __fp16 h2 __attribute__((ext_vector_type(2)));
typedef float f32x4 __attribute__((ext_vector_type(4)));

// ws layout: [0,768) h8 frags: hidden A[(l*2+t)*64+q]; [768,832) h8: A_out[q];
// then (byte 13312) float Winp[32][3].
#define WS_WINP_BYTE 13312

__device__ __forceinline__ int mu_map(int k) {
    int g = k >> 3, j = k & 7;
    return (j < 4) ? (4 * g + j) : (16 + 4 * g + (j & 3));
}

__global__ __launch_bounds__(256) void prep_kernel(
    const float* __restrict__ w_in, const float* __restrict__ ws,
    const float* __restrict__ w_out, __fp16* __restrict__ wsA,
    float* __restrict__ winp)
{
    int tid = threadIdx.x;
    // hidden A-frags: 12 combos (layer l, tile t) x 64 lanes
    for (int u = tid; u < 12 * 64; u += 256) {
        int q = u & 63, combo = u >> 6;
        int l = combo >> 1, t = combo & 1;
        int m = t * 16 + (q & 15);           // out channel (row)
        for (int j = 0; j < 8; ++j) {
            int k = (q >> 4) * 8 + j;        // physical k column (0..31)
            int c = mu_map(k);               // logical input channel
            float v = (m < HID && c < HID) ? ws[(l * HID + m) * HID + c] * TANH_SCALE : 0.0f;
            wsA[u * 8 + j] = (__fp16)v;
        }
    }
    // output A-frag
    if (tid < 64) {
        int q = tid, m = q & 15;
        for (int j = 0; j < 8; ++j) {
            int k = (q >> 4) * 8 + j;
            int c = mu_map(k);
            float v = (m < 3 && c < HID) ? w_out[m * HID + c] * SIG_SCALE : 0.0f;
            wsA[(12 * 64 + q) * 8 + j] = (__fp16)v;
        }
    }
    // input weights, mu-ordered rows: winp[k][c] = w_in[mu(k)][c] * scale
    if (tid < 32) {
        int k = tid, c = mu_map(k);
        for (int ci = 0; ci < 3; ++ci)
            winp[k * 3 + ci] = (c < HID) ? w_in[c * 3 + ci] * TANH_SCALE : 0.0f;
    }
}

__device__ __forceinline__ float tanh_scaled(float acc) {   // acc = 2log2e * z
    float e = __builtin_amdgcn_exp2f(acc);
    float r = __builtin_amdgcn_rcpf(e + 1.0f);
    return fmaf(-2.0f, r, 1.0f);
}
__device__ __forceinline__ float sig_scaled(float acc) {    // acc = -log2e * z
    float e = __builtin_amdgcn_exp2f(acc);
    return __builtin_amdgcn_rcpf(e + 1.0f);
}

__global__ __launch_bounds__(256, 1) void simplenet_kernel(
    const float* __restrict__ x,     // [4,3,1024,1024]
    const h8* __restrict__ wsA,      // packed A fragments
    const float* __restrict__ winp,  // [32][3] mu-ordered, scaled
    float* __restrict__ out)         // [4,3,1024,1024]
{
    const int lane = threadIdx.x & 63;
    const int wgid = blockIdx.x * 4 + (threadIdx.x >> 6);
    const int g = lane >> 4, col = lane & 15;

    // hoist all weight fragments into registers (reused over 16 iterations)
    h8 A[12];
#pragma unroll
    for (int i = 0; i < 12; ++i) A[i] = wsA[i * 64 + lane];
    h8 Aout = wsA[12 * 64 + lane];

    // input-layer rows this lane computes: mu-ordered rows 8g..8g+7, 3 floats each
    float wi[24];
    {
        const f32x4* wp4 = (const f32x4*)(winp + 8 * g * 3);  // 24 floats, 16B-aligned
#pragma unroll
        for (int i = 0; i < 6; ++i) {
            f32x4 v = wp4[i];
            wi[i * 4 + 0] = v.x; wi[i * 4 + 1] = v.y; wi[i * 4 + 2] = v.z; wi[i * 4 + 3] = v.w;
        }
    }

    const int pbase = wgid * 512;           // 512 consecutive pixels per wave
    const int b = pbase >> 20;              // image index (512 | 2^20: no straddle)
    const int hwb = pbase & (HW_PIX - 1);
    const float* xb = x + (size_t)b * 3 * HW_PIX;
    float* ob = out + (size_t)b * 3 * HW_PIX;

    for (int it = 0; it < 16; ++it) {
        const int hw0 = hwb + it * 32;

        // ---- input layer: each lane computes B elements j=0..7 (chs mu(8g+j)) ----
        h8 B[2];
#pragma unroll
        for (int n = 0; n < 2; ++n) {
            const int hw = hw0 + n * 16 + col;
            float x0 = xb[0 * HW_PIX + hw];
            float x1 = xb[1 * HW_PIX + hw];
            float x2 = xb[2 * HW_PIX + hw];
            float th[8];
#pragma unroll
            for (int j = 0; j < 8; ++j) {
                float acc = wi[j * 3 + 0] * x0;
                acc = fmaf(wi[j * 3 + 1], x1, acc);
                acc = fmaf(wi[j * 3 + 2], x2, acc);
                th[j] = tanh_scaled(acc);
            }
            union { h8 v; h2 p[4]; } u;
#pragma unroll
            for (int pr = 0; pr < 4; ++pr)
                u.p[pr] = __builtin_amdgcn_cvt_pkrtz(th[pr * 2], th[pr * 2 + 1]);
            B[n] = u.v;
        }

        // ---- 6 hidden layers: 2 M-tiles x 2 N-tiles MFMA, tanh, repack ----
#pragma unroll
        for (int l = 0; l < 6; ++l) {
#pragma unroll
            for (int n = 0; n < 2; ++n) {
                f32x4 zero = {0.0f, 0.0f, 0.0f, 0.0f};
                f32x4 d0 = __builtin_amdgcn_mfma_f32_16x16x32_f16(A[l * 2 + 0], B[n], zero, 0, 0, 0);
                f32x4 d1 = __builtin_amdgcn_mfma_f32_16x16x32_f16(A[l * 2 + 1], B[n], zero, 0, 0, 0);
                // D tile t reg r = out-ch (t*16 + 4g + r); next B elem j:
                //   j<4 -> tile0 reg j ; j>=4 -> tile1 reg j-4   (mu relabeling)
                union { h8 v; h2 p[4]; } u;
                u.p[0] = __builtin_amdgcn_cvt_pkrtz(tanh_scaled(d0.x), tanh_scaled(d0.y));
                u.p[1] = __builtin_amdgcn_cvt_pkrtz(tanh_scaled(d0.z), tanh_scaled(d0.w));
                u.p[2] = __builtin_amdgcn_cvt_pkrtz(tanh_scaled(d1.x), tanh_scaled(d1.y));
                u.p[3] = __builtin_amdgcn_cvt_pkrtz(tanh_scaled(d1.z), tanh_scaled(d1.w));
                B[n] = u.v;
            }
        }

        // ---- output layer: 3 channels live in rows 0..2 (g==0 lanes) ----
#pragma unroll
        for (int n = 0; n < 2; ++n) {
            f32x4 zero = {0.0f, 0.0f, 0.0f, 0.0f};
            f32x4 d = __builtin_amdgcn_mfma_f32_16x16x32_f16(Aout, B[n], zero, 0, 0, 0);
            if (g == 0) {
                const int hw = hw0 + n * 16 + col;
                ob[0 * HW_PIX + hw] = sig_scaled(d.x);
                ob[1 * HW_PIX + hw] = sig_scaled(d.y);
                ob[2 * HW_PIX + hw] = sig_scaled(d.z);
            }
        }
    }
}

extern "C" void kernel_launch(void* const* d_in, const int* in_sizes, int n_in,
                              void* d_out, int out_size, void* d_ws, size_t ws_size,
                              hipStream_t stream) {
    const float* x     = (const float*)d_in[0];
    const float* w_in  = (const float*)d_in[1];
    const float* ws    = (const float*)d_in[2];
    const float* w_out = (const float*)d_in[3];
    float* out         = (float*)d_out;

    __fp16* wsA = (__fp16*)d_ws;
    float* winp = (float*)((char*)d_ws + WS_WINP_BYTE);

    hipLaunchKernelGGL(prep_kernel, dim3(1), dim3(256), 0, stream,
                       w_in, ws, w_out, wsA, winp);

    // 8192 waves x 16 iters x 32 px = 4Mi pixels, exact
    hipLaunchKernelGGL(simplenet_kernel, dim3(2048), dim3(256), 0, stream,
                       x, (const h8*)d_ws, winp, out);
}